// Round 2
// baseline (168.326 us; speedup 1.0000x reference)
//
#include <hip/hip_runtime.h>
#include <hip/hip_fp16.h>

// ---------------- problem constants ----------------
#define NIMG 32
#define CH   3
#define HIN  256
#define WIN  256
#define MARG 38          // 2*HZ_PAD + 32
#define HP   332         // HIN + 2*MARG
#define WP   332
#define HU   664         // 2*HP
#define WU   664
#define HO   256
#define WO   256

// plain fp16 upsampled intermediate, padded row pitch (cols 664..671 are zeros)
#define UPITCH  672
#define CHELEMS (664 * 672)

// LDS staging window for the warp (per 32x32 output tile)
#define PH 132            // max rows
#define PW 152            // max cols (19 x 8-elem slots), 8-aligned base
#define PWB (PW * 2)      // row pitch in bytes (304)

typedef __fp16 h2 __attribute__((ext_vector_type(2)));

// reflect (edge-excluding) for original 256-range, valid for r in [-255, 510]
__device__ __forceinline__ int refl(int r) {
    r = (r < 0) ? -r : r;
    return (r > 255) ? (510 - r) : r;
}

// ---------------- per-image affine coefficients ----------------
__global__ void k_setup(const float* __restrict__ th, const float* __restrict__ ls,
                        const float* __restrict__ txp, const float* __restrict__ typ,
                        float* __restrict__ coef) {
    int n = blockIdx.x * blockDim.x + threadIdx.x;
    if (n >= NIMG) return;
    float c  = cosf(th[n]);
    float sn = sinf(th[n]);
    float inv_s = 1.0f / expf(ls[n]);
    float tX = -txp[n] * (float)WIN;
    float tY = -typ[n] * (float)HIN;
    float A00 = inv_s * c,    A01 = inv_s * sn,  A02 = inv_s * (c * tX + sn * tY);
    float A10 = -inv_s * sn,  A11 = inv_s * c,   A12 = inv_s * (-sn * tX + c * tY);
    A02 *= 2.0f; A12 *= 2.0f;
    A02 += 0.5f * (A00 + A01) - 0.5f;
    A12 += 0.5f * (A10 + A11) - 0.5f;
    const float Wu = (float)HU, Hu = (float)HU;
    const float Wt = 524.0f, Ht = 524.0f;
    float B00 = A00 * (2.0f / Wu) * (Wt * 0.5f);
    float B01 = A01 * (2.0f / Wu) * (Ht * 0.5f);
    float B02 = A02 * (2.0f / Wu);
    float B10 = A10 * (2.0f / Hu) * (Wt * 0.5f);
    float B11 = A11 * (2.0f / Hu) * (Ht * 0.5f);
    float B12 = A12 * (2.0f / Hu);
    float cxx = B00 * Wu / Wt;
    float cxy = B01 * Wu / Ht;
    float cx0 = 0.5f * ((B00 * (1.0f / Wt - 1.0f) + B01 * (1.0f / Ht - 1.0f) + B02 + 1.0f) * Wu - 1.0f);
    float cyx = B10 * Hu / Wt;
    float cyy = B11 * Hu / Ht;
    float cy0 = 0.5f * ((B10 * (1.0f / Wt - 1.0f) + B11 * (1.0f / Ht - 1.0f) + B12 + 1.0f) * Hu - 1.0f);
    coef[n * 6 + 0] = cxx;
    coef[n * 6 + 1] = cxy;
    coef[n * 6 + 2] = cx0;
    coef[n * 6 + 3] = cyx;
    coef[n * 6 + 4] = cyy;
    coef[n * 6 + 5] = cy0;
}

__device__ __forceinline__ unsigned hbits(float a, float b) {
    __half2 h = __floats2half2_rn(a, b);
    return *(unsigned*)&h;
}

// ---------------- KA: fused reflect-pad + 2x upsample -> plain fp16 (padded pitch) ----------------
__global__ void __launch_bounds__(256) k_up2(const float* __restrict__ img,
                                             const float* __restrict__ hz,
                                             __fp16* __restrict__ ups, int ch0) {
    __shared__ float s_in[38][40];    // 38 rows x 39 cols used
    __shared__ float s_mid[38][68];   // cols 0..65 used
    int ch  = blockIdx.z;
    int ty0 = blockIdx.y * 64;
    int tx0 = blockIdx.x * 64;
    int jy0 = (ty0 >> 1) - 3;
    int jx0 = (tx0 >> 1) - 3;
    int tid = threadIdx.x;
    float f[12];
#pragma unroll
    for (int i = 0; i < 12; ++i) f[i] = hz[i];
    const float* base = img + (size_t)(ch0 + ch) * HIN * WIN;

    // stage 1: padded input patch (38 x 39), zero outside [0,332)^2
    for (int i = tid; i < 38 * 39; i += 256) {
        int ly = i / 39, lx = i - ly * 39;
        int gy = jy0 + ly, gx = jx0 + lx;
        float v = 0.0f;
        if (gy >= 0 && gy < HP && gx >= 0 && gx < WP)
            v = base[refl(gy - MARG) * WIN + refl(gx - MARG)];
        s_in[ly][lx] = v;
    }
    __syncthreads();

    // stage 2: horizontal upsample, cols 0..65
    for (int i = tid; i < 38 * 33; i += 256) {
        int j = i % 33, ly = i / 33;
        float t0 = s_in[ly][j + 0], t1 = s_in[ly][j + 1], t2 = s_in[ly][j + 2];
        float t3 = s_in[ly][j + 3], t4 = s_in[ly][j + 4], t5 = s_in[ly][j + 5];
        float t6 = s_in[ly][j + 6];
        float ev = f[11] * t0 + f[9] * t1 + f[7] * t2 + f[5] * t3 + f[3] * t4 + f[1] * t5;
        float od = f[10] * t1 + f[8] * t2 + f[6] * t3 + f[4] * t4 + f[2] * t5 + f[0] * t6;
        s_mid[ly][2 * j]     = ev * 2.0f;
        s_mid[ly][2 * j + 1] = od * 2.0f;
    }
    __syncthreads();

    // stage 3: vertical upsample; each thread: 4 cols x 2 row-pairs; 8B stores
    int qx = tid & 15;
    int mg = tid >> 4;
    int gx0 = tx0 + 4 * qx;
    __fp16* upch = ups + (size_t)ch * CHELEMS;
#pragma unroll
    for (int pi = 0; pi < 2; ++pi) {
        int m = mg + pi * 16;
        int gy = ty0 + 2 * m;
        if (gy < HU) {
            if (gx0 + 3 < WU) {
                float4 r0 = *(const float4*)&s_mid[m + 0][4 * qx];
                float4 r1 = *(const float4*)&s_mid[m + 1][4 * qx];
                float4 r2 = *(const float4*)&s_mid[m + 2][4 * qx];
                float4 r3 = *(const float4*)&s_mid[m + 3][4 * qx];
                float4 r4 = *(const float4*)&s_mid[m + 4][4 * qx];
                float4 r5 = *(const float4*)&s_mid[m + 5][4 * qx];
                float4 r6 = *(const float4*)&s_mid[m + 6][4 * qx];
                float v0 = f[11]*r0.x + f[9]*r1.x + f[7]*r2.x + f[5]*r3.x + f[3]*r4.x + f[1]*r5.x;
                float v1 = f[11]*r0.y + f[9]*r1.y + f[7]*r2.y + f[5]*r3.y + f[3]*r4.y + f[1]*r5.y;
                float v2 = f[11]*r0.z + f[9]*r1.z + f[7]*r2.z + f[5]*r3.z + f[3]*r4.z + f[1]*r5.z;
                float v3 = f[11]*r0.w + f[9]*r1.w + f[7]*r2.w + f[5]*r3.w + f[3]*r4.w + f[1]*r5.w;
                float w0 = f[10]*r1.x + f[8]*r2.x + f[6]*r3.x + f[4]*r4.x + f[2]*r5.x + f[0]*r6.x;
                float w1 = f[10]*r1.y + f[8]*r2.y + f[6]*r3.y + f[4]*r4.y + f[2]*r5.y + f[0]*r6.y;
                float w2 = f[10]*r1.z + f[8]*r2.z + f[6]*r3.z + f[4]*r4.z + f[2]*r5.z + f[0]*r6.z;
                float w3 = f[10]*r1.w + f[8]*r2.w + f[6]*r3.w + f[4]*r4.w + f[2]*r5.w + f[0]*r6.w;
                uint2 qe, qo;
                qe.x = hbits(v0 * 2.0f, v1 * 2.0f); qe.y = hbits(v2 * 2.0f, v3 * 2.0f);
                qo.x = hbits(w0 * 2.0f, w1 * 2.0f); qo.y = hbits(w2 * 2.0f, w3 * 2.0f);
                *(uint2*)&upch[(size_t)gy * UPITCH + gx0]       = qe;
                *(uint2*)&upch[(size_t)(gy + 1) * UPITCH + gx0] = qo;
            } else if (gx0 >= WU && gx0 < UPITCH) {
                uint2 z; z.x = 0u; z.y = 0u;   // zero pad cols 664..671
                *(uint2*)&upch[(size_t)gy * UPITCH + gx0]       = z;
                *(uint2*)&upch[(size_t)(gy + 1) * UPITCH + gx0] = z;
            }
        }
    }
}

// ---------------- shared downsample phases (ph2: horizontal, ph3: vertical) ----------------
__device__ __forceinline__ void dn_phases(const float* __restrict__ hz,
                                          const __fp16* s_wh, h2* s_m2,
                                          float* __restrict__ outc,
                                          int ty0, int tx0, int tid) {
    float f[12];
#pragma unroll
    for (int i = 0; i < 12; ++i) f[i] = hz[i];
    h2 Fe[6];
#pragma unroll
    for (int i = 0; i < 6; ++i) { Fe[i][0] = (__fp16)f[2 * i]; Fe[i][1] = (__fp16)f[2 * i + 1]; }

    // phase 2: horizontal downsample via fdot2 on fp16 pairs -> s_m2
    for (int i = tid; i < 74 * 16; i += 512) {
        int j = i & 15, lwy = i >> 4;
        const __fp16* r = &s_wh[lwy * 82 + 4 * j];
        h2 P0 = *(const h2*)(r + 0);
        h2 P1 = *(const h2*)(r + 2);
        h2 P2 = *(const h2*)(r + 4);
        h2 P3 = *(const h2*)(r + 6);
        h2 P4 = *(const h2*)(r + 8);
        h2 P5 = *(const h2*)(r + 10);
        h2 P6 = *(const h2*)(r + 12);
        float ev = __builtin_amdgcn_fdot2(P0, Fe[0],
                   __builtin_amdgcn_fdot2(P1, Fe[1],
                   __builtin_amdgcn_fdot2(P2, Fe[2],
                   __builtin_amdgcn_fdot2(P3, Fe[3],
                   __builtin_amdgcn_fdot2(P4, Fe[4],
                   __builtin_amdgcn_fdot2(P5, Fe[5], 0.0f, false), false), false), false), false), false);
        float od = __builtin_amdgcn_fdot2(P1, Fe[0],
                   __builtin_amdgcn_fdot2(P2, Fe[1],
                   __builtin_amdgcn_fdot2(P3, Fe[2],
                   __builtin_amdgcn_fdot2(P4, Fe[3],
                   __builtin_amdgcn_fdot2(P5, Fe[4],
                   __builtin_amdgcn_fdot2(P6, Fe[5], 0.0f, false), false), false), false), false), false);
        h2 sm; sm[0] = (__fp16)ev; sm[1] = (__fp16)od;
        s_m2[lwy * 17 + j] = sm;
    }
    __syncthreads();

    // phase 3: vertical downsample, (even,odd) column pair per thread
    {
        int j = tid & 15, my = tid >> 4;   // tid<512 == 32x16 exactly
        float ev = 0.0f, od = 0.0f;
#pragma unroll
        for (int t = 0; t < 12; ++t) {
            h2 h = s_m2[(2 * my + t) * 17 + j];
            ev += f[t] * (float)h[0];
            od += f[t] * (float)h[1];
        }
        float2 o; o.x = ev; o.y = od;
        *(float2*)&outc[(size_t)(ty0 + my) * WO + (tx0 + 2 * j)] = o;
    }
}

// ---------------- KB: 3-channel LDS-staged bilinear warp + 2x downsample ----------------
// One block = one image-tile, all 3 channels. Channel 0 computes full addressing and
// caches {packed LDS addr | sh | write addr} and the packed bilinear x-weights in VGPRs;
// channels 1-2 replay from cache (wyf recomputed in f32, bit-identical arithmetic).
__global__ void __launch_bounds__(512) k_warpdn(const __fp16* __restrict__ ups,
                                                const float* __restrict__ coef,
                                                const float* __restrict__ hz,
                                                float* __restrict__ out,
                                                int n0) {
    __shared__ __align__(16) unsigned char s_raw[PH * PWB];      // 40.1 KB
    __shared__ __fp16 s_wh[80 * 82];                             // 13.1 KB
    __fp16* s_src = (__fp16*)s_raw;
    h2*     s_m2  = (h2*)s_raw;      // aliases s_src (disjoint live ranges)

    int z   = blockIdx.z;            // image within chunk
    int ty0 = blockIdx.y * 32;
    int tx0 = blockIdx.x * 32;
    int tid = threadIdx.x;
    const float* cf = coef + (size_t)(n0 + z) * 6;
    float cxx = cf[0], cxy = cf[1], cx0 = cf[2];
    float cyx = cf[3], cyy = cf[4], cy0 = cf[5];
    int wy0 = 2 * ty0 + 1, wx0 = 2 * tx0 + 1;
    float wx0f = (float)wx0, wy0f = (float)wy0;

    // source bbox from tile corners (affine -> corners bound everything); same for 3 ch
    float ix00 = cxx * wx0f + cxy * wy0f + cx0;
    float iy00 = cyx * wx0f + cyy * wy0f + cy0;
    float dxx = cxx * 73.0f, dxy = cxy * 73.0f;
    float dyx = cyx * 73.0f, dyy = cyy * 73.0f;
    float ixmin = ix00 + fminf(dxx, 0.0f) + fminf(dxy, 0.0f);
    float ixmax = ix00 + fmaxf(dxx, 0.0f) + fmaxf(dxy, 0.0f);
    float iymin = iy00 + fminf(dyx, 0.0f) + fminf(dyy, 0.0f);
    float iymax = iy00 + fmaxf(dyx, 0.0f) + fmaxf(dyy, 0.0f);
    int x_lo = (int)floorf(ixmin) - 1;
    int x_base = x_lo & ~7;
    int x_hi = (int)floorf(ixmax) + 2;
    int y_lo = (int)floorf(iymin) - 1;
    int y_hi = (int)floorf(iymax) + 2;
    int Rn = y_hi - y_lo + 1;
    int Wn = x_hi - x_base + 1;
    bool ldsok = (Rn <= PH) && (Wn <= PW);

    int wave = __builtin_amdgcn_readfirstlane(tid >> 6);   // 0..7
    int lane = tid & 63;
    int ply = lane >> 3, plx = lane & 7;
    float ix_l = cxx * (float)(wx0 + plx) + cxy * (float)(wy0 + ply) + cx0;
    float iy_l = cyx * (float)(wx0 + plx) + cyy * (float)(wy0 + ply) + cy0;
    float c8xx = 8.0f * cxx, c8xy = 8.0f * cxy;
    float c8yx = 8.0f * cyx, c8yy = 8.0f * cyy;

    if (ldsok) {
        int A[13];                    // bits[15:0]=LDS byte addr, bit16=lx&1, bits[29:17]=s_wh addr
        h2  WV[13];                   // packed (1-wx, wx) fp16 weights (exact round-0 arithmetic)
        int slotsPerRow = (Wn + 7) >> 3;          // <= 19

        for (int c = 0; c < CH; ++c) {
            const __fp16* upc = ups + (size_t)(z * CH + c) * CHELEMS;
            const unsigned short* us = (const unsigned short*)upc;

            // ---- stage bbox into LDS, coalesced 16B chunks, zero-fill OOB ----
            int items = Rn * (PW / 8);
            for (int i = tid; i < items; i += 512) {
                int row  = i / (PW / 8);
                int slot = i - row * (PW / 8);
                if (slot >= slotsPerRow) continue;    // unread slots stay garbage
                int gy = y_lo + row;
                int gx = x_base + slot * 8;
                uint4 val;
                if (gy >= 0 && gy < HU && gx >= 0 && gx <= UPITCH - 8) {
                    val = *(const uint4*)&upc[(size_t)gy * UPITCH + gx];
                } else if (gy >= 0 && gy < HU) {
                    unsigned part[4];
#pragma unroll
                    for (int k = 0; k < 4; ++k) {
                        int ga = gx + 2 * k, gb = ga + 1;
                        unsigned lo = (ga >= 0 && ga < WU) ? (unsigned)us[(size_t)gy * UPITCH + ga] : 0u;
                        unsigned hi = (gb >= 0 && gb < WU) ? (unsigned)us[(size_t)gy * UPITCH + gb] : 0u;
                        part[k] = lo | (hi << 16);
                    }
                    val.x = part[0]; val.y = part[1]; val.z = part[2]; val.w = part[3];
                } else {
                    val.x = 0u; val.y = 0u; val.z = 0u; val.w = 0u;
                }
                *(uint4*)&s_src[row * PW + slot * 8] = val;
            }
            __syncthreads();

            if (c == 0) {
                // ---- full gather + build per-sample cache ----
#pragma unroll
                for (int k = 0; k < 13; ++k) {
                    A[k] = -1;
                    int pp = wave + 8 * k;
                    if (pp < 100) {
                        int py = (pp * 205) >> 11;     // pp/10, exact for 0..99
                        int px = pp - py * 10;
                        int lwy = py * 8 + ply;
                        int lwx = px * 8 + plx;
                        if (lwy < 74 && lwx < 74) {
                            float ix = ix_l + (float)px * c8xx + (float)py * c8xy;
                            float iy = iy_l + (float)px * c8yx + (float)py * c8yy;
                            float fx = floorf(ix), fy = floorf(iy);
                            float wx = ix - fx, wyf = iy - fy;
                            int lx = (int)fx - x_base;
                            int ly = (int)fy - y_lo;
                            int e  = lx & ~1;
                            int a_rd = ly * PWB + 2 * e;
                            unsigned sh = ((unsigned)lx & 1u) << 4;
                            int waddr = lwy * 82 + lwx;
                            A[k]  = a_rd | ((lx & 1) << 16) | (waddr << 17);
                            h2 wv = __builtin_amdgcn_cvt_pkrtz(1.0f - wx, wx);
                            WV[k] = wv;
                            const unsigned* p0 = (const unsigned*)(s_raw + a_rd);
                            unsigned w0 = p0[0], w1 = p0[1];
                            const unsigned* p1 = (const unsigned*)(s_raw + a_rd + PWB);
                            unsigned w2 = p1[0], w3 = p1[1];
                            unsigned u0 = __builtin_amdgcn_alignbit(w1, w0, sh);
                            unsigned u1 = __builtin_amdgcn_alignbit(w3, w2, sh);
                            h2 h0; *(unsigned*)&h0 = u0;
                            h2 h1; *(unsigned*)&h1 = u1;
                            float r0 = __builtin_amdgcn_fdot2(h0, wv, 0.0f, false);
                            float r1 = __builtin_amdgcn_fdot2(h1, wv, 0.0f, false);
                            s_wh[waddr] = (__fp16)(r0 + wyf * (r1 - r0));
                        }
                    }
                }
            } else {
                // ---- replay gather from cache (addressing + weights reused) ----
#pragma unroll
                for (int k = 0; k < 13; ++k) {
                    int a = A[k];
                    if (a >= 0) {
                        int a_rd = a & 0xFFFF;
                        unsigned sh = ((unsigned)a >> 12) & 16u;
                        int waddr = (int)((unsigned)a >> 17);
                        int pp = wave + 8 * k;            // wave-uniform (SALU)
                        int py = (pp * 205) >> 11;
                        int px = pp - py * 10;
                        float iy = iy_l + (float)px * c8yx + (float)py * c8yy;
                        float wyf = iy - floorf(iy);
                        const unsigned* p0 = (const unsigned*)(s_raw + a_rd);
                        unsigned w0 = p0[0], w1 = p0[1];
                        const unsigned* p1 = (const unsigned*)(s_raw + a_rd + PWB);
                        unsigned w2 = p1[0], w3 = p1[1];
                        unsigned u0 = __builtin_amdgcn_alignbit(w1, w0, sh);
                        unsigned u1 = __builtin_amdgcn_alignbit(w3, w2, sh);
                        h2 h0; *(unsigned*)&h0 = u0;
                        h2 h1; *(unsigned*)&h1 = u1;
                        h2 wv = WV[k];
                        float r0 = __builtin_amdgcn_fdot2(h0, wv, 0.0f, false);
                        float r1 = __builtin_amdgcn_fdot2(h1, wv, 0.0f, false);
                        s_wh[waddr] = (__fp16)(r0 + wyf * (r1 - r0));
                    }
                }
            }
            __syncthreads();

            dn_phases(hz, s_wh, s_m2,
                      out + (size_t)((n0 + z) * CH + c) * HO * WO, ty0, tx0, tid);
            if (c < CH - 1) __syncthreads();
        }
    } else {
        // ---- fallback: guarded global gather per channel (rare: bbox too large) ----
        for (int c = 0; c < CH; ++c) {
            const __fp16* upc = ups + (size_t)(z * CH + c) * CHELEMS;
            for (int pp = wave; pp < 100; pp += 8) {
                int py = (pp * 205) >> 11;
                int px = pp - py * 10;
                int lwy = py * 8 + ply;
                int lwx = px * 8 + plx;
                if (lwy < 74 && lwx < 74) {
                    float ix = ix_l + (float)px * c8xx + (float)py * c8xy;
                    float iy = iy_l + (float)px * c8yx + (float)py * c8yy;
                    float fx = floorf(ix), fy = floorf(iy);
                    float wx = ix - fx, wyf = iy - fy;
                    int x0 = (int)fx, y0 = (int)fy;
                    int xc0 = min(max(x0, 0), WU - 1);
                    int xc1 = min(max(x0 + 1, 0), WU - 1);
                    int yc0 = min(max(y0, 0), HU - 1);
                    int yc1 = min(max(y0 + 1, 0), HU - 1);
                    float mx0 = (x0 >= 0 && x0 < WU) ? 1.0f : 0.0f;
                    float mx1 = (x0 >= -1 && x0 < WU - 1) ? 1.0f : 0.0f;
                    float my0 = (y0 >= 0 && y0 < HU) ? 1.0f : 0.0f;
                    float my1 = (y0 >= -1 && y0 < HU - 1) ? 1.0f : 0.0f;
                    float t00 = (float)upc[(size_t)yc0 * UPITCH + xc0] * mx0;
                    float t01 = (float)upc[(size_t)yc0 * UPITCH + xc1] * mx1;
                    float t10 = (float)upc[(size_t)yc1 * UPITCH + xc0] * mx0;
                    float t11 = (float)upc[(size_t)yc1 * UPITCH + xc1] * mx1;
                    float r0 = t00 + wx * (t01 - t00);
                    float r1 = t10 + wx * (t11 - t10);
                    s_wh[lwy * 82 + lwx] = (__fp16)(r0 * (1.0f - wyf) * my0 + r1 * wyf * my1);
                }
            }
            __syncthreads();

            dn_phases(hz, s_wh, s_m2,
                      out + (size_t)((n0 + z) * CH + c) * HO * WO, ty0, tx0, tid);
            if (c < CH - 1) __syncthreads();
        }
    }
}

// ---------------- launch ----------------
extern "C" void kernel_launch(void* const* d_in, const int* in_sizes, int n_in,
                              void* d_out, int out_size, void* d_ws, size_t ws_size,
                              hipStream_t stream) {
    const float* images = (const float*)d_in[0];
    const float* theta  = (const float*)d_in[1];
    const float* log_s  = (const float*)d_in[2];
    const float* tx     = (const float*)d_in[3];
    const float* ty     = (const float*)d_in[4];
    const float* hz     = (const float*)d_in[5];
    float* out = (float*)d_out;
    float* ws  = (float*)d_ws;

    // intermediate: plain fp16 padded-pitch, [cn*CH] channels.
    // cn=16 (42.8 MB) keeps the chunk L3-resident between up2 and warpdn
    // (round-8 evidence: FETCH ~ 0 at this size; cn=32's 86 MB did not stay).
    int cn = 16;
    while (cn > 1) {
        size_t needed = 1024 + (size_t)cn * CH * CHELEMS * sizeof(__fp16);
        if (needed <= ws_size) break;
        cn >>= 1;
    }
    float* coef = ws;
    __fp16* upsb = (__fp16*)(ws + 256);

    hipLaunchKernelGGL(k_setup, dim3(1), dim3(32), 0, stream, theta, log_s, tx, ty, coef);

    const int TA = (HU + 63) / 64;    // 11
    for (int n0 = 0; n0 < NIMG; n0 += cn) {
        int nch = cn * CH;
        int ch0 = n0 * CH;
        hipLaunchKernelGGL(k_up2, dim3(TA, TA, nch), dim3(256), 0, stream,
                           images, hz, upsb, ch0);
        hipLaunchKernelGGL(k_warpdn, dim3(WO / 32, HO / 32, cn), dim3(512), 0, stream,
                           upsb, coef, hz, out, n0);
    }
}

// Round 3
// 110.892 us; speedup vs baseline: 1.5179x; 1.5179x over previous
//
#include <hip/hip_runtime.h>
#include <hip/hip_fp16.h>

// ---------------- problem constants ----------------
#define NIMG 32
#define CH   3
#define HIN  256
#define WIN  256
#define MARG 38          // 2*HZ_PAD + 32
#define HP   332         // HIN + 2*MARG
#define WP   332
#define HU   664         // 2*HP
#define WU   664
#define HO   256
#define WO   256

// plain fp16 upsampled intermediate, padded row pitch (cols 664..671 are zeros)
#define UPITCH  672
#define CHELEMS (664 * 672)

// LDS staging window for the warp (per 32x32 output tile)
#define PH 132            // max rows
#define PW 152            // max cols (19 x 8-elem slots), 8-aligned base
#define PWB (PW * 2)      // row pitch in bytes (304)

typedef __fp16 h2 __attribute__((ext_vector_type(2)));

// reflect (edge-excluding) for original 256-range, valid for r in [-255, 510]
__device__ __forceinline__ int refl(int r) {
    r = (r < 0) ? -r : r;
    return (r > 255) ? (510 - r) : r;
}

// ---------------- per-image affine coefficients ----------------
__global__ void k_setup(const float* __restrict__ th, const float* __restrict__ ls,
                        const float* __restrict__ txp, const float* __restrict__ typ,
                        float* __restrict__ coef) {
    int n = blockIdx.x * blockDim.x + threadIdx.x;
    if (n >= NIMG) return;
    float c  = cosf(th[n]);
    float sn = sinf(th[n]);
    float inv_s = 1.0f / expf(ls[n]);
    float tX = -txp[n] * (float)WIN;
    float tY = -typ[n] * (float)HIN;
    float A00 = inv_s * c,    A01 = inv_s * sn,  A02 = inv_s * (c * tX + sn * tY);
    float A10 = -inv_s * sn,  A11 = inv_s * c,   A12 = inv_s * (-sn * tX + c * tY);
    A02 *= 2.0f; A12 *= 2.0f;
    A02 += 0.5f * (A00 + A01) - 0.5f;
    A12 += 0.5f * (A10 + A11) - 0.5f;
    const float Wu = (float)HU, Hu = (float)HU;
    const float Wt = 524.0f, Ht = 524.0f;
    float B00 = A00 * (2.0f / Wu) * (Wt * 0.5f);
    float B01 = A01 * (2.0f / Wu) * (Ht * 0.5f);
    float B02 = A02 * (2.0f / Wu);
    float B10 = A10 * (2.0f / Hu) * (Wt * 0.5f);
    float B11 = A11 * (2.0f / Hu) * (Ht * 0.5f);
    float B12 = A12 * (2.0f / Hu);
    float cxx = B00 * Wu / Wt;
    float cxy = B01 * Wu / Ht;
    float cx0 = 0.5f * ((B00 * (1.0f / Wt - 1.0f) + B01 * (1.0f / Ht - 1.0f) + B02 + 1.0f) * Wu - 1.0f);
    float cyx = B10 * Hu / Wt;
    float cyy = B11 * Hu / Ht;
    float cy0 = 0.5f * ((B10 * (1.0f / Wt - 1.0f) + B11 * (1.0f / Ht - 1.0f) + B12 + 1.0f) * Hu - 1.0f);
    coef[n * 6 + 0] = cxx;
    coef[n * 6 + 1] = cxy;
    coef[n * 6 + 2] = cx0;
    coef[n * 6 + 3] = cyx;
    coef[n * 6 + 4] = cyy;
    coef[n * 6 + 5] = cy0;
}

__device__ __forceinline__ unsigned hbits(float a, float b) {
    __half2 h = __floats2half2_rn(a, b);
    return *(unsigned*)&h;
}

// ---------------- KA: fused reflect-pad + 2x upsample -> plain fp16 (padded pitch) ----------------
__global__ void __launch_bounds__(256) k_up2(const float* __restrict__ img,
                                             const float* __restrict__ hz,
                                             __fp16* __restrict__ ups, int ch0) {
    __shared__ float s_in[38][40];    // 38 rows x 39 cols used
    __shared__ float s_mid[38][68];   // cols 0..65 used
    int ch  = blockIdx.z;
    int ty0 = blockIdx.y * 64;
    int tx0 = blockIdx.x * 64;
    int jy0 = (ty0 >> 1) - 3;
    int jx0 = (tx0 >> 1) - 3;
    int tid = threadIdx.x;
    float f[12];
#pragma unroll
    for (int i = 0; i < 12; ++i) f[i] = hz[i];
    const float* base = img + (size_t)(ch0 + ch) * HIN * WIN;

    // stage 1: padded input patch (38 x 39), zero outside [0,332)^2
    for (int i = tid; i < 38 * 39; i += 256) {
        int ly = i / 39, lx = i - ly * 39;
        int gy = jy0 + ly, gx = jx0 + lx;
        float v = 0.0f;
        if (gy >= 0 && gy < HP && gx >= 0 && gx < WP)
            v = base[refl(gy - MARG) * WIN + refl(gx - MARG)];
        s_in[ly][lx] = v;
    }
    __syncthreads();

    // stage 2: horizontal upsample, cols 0..65
    for (int i = tid; i < 38 * 33; i += 256) {
        int j = i % 33, ly = i / 33;
        float t0 = s_in[ly][j + 0], t1 = s_in[ly][j + 1], t2 = s_in[ly][j + 2];
        float t3 = s_in[ly][j + 3], t4 = s_in[ly][j + 4], t5 = s_in[ly][j + 5];
        float t6 = s_in[ly][j + 6];
        float ev = f[11] * t0 + f[9] * t1 + f[7] * t2 + f[5] * t3 + f[3] * t4 + f[1] * t5;
        float od = f[10] * t1 + f[8] * t2 + f[6] * t3 + f[4] * t4 + f[2] * t5 + f[0] * t6;
        s_mid[ly][2 * j]     = ev * 2.0f;
        s_mid[ly][2 * j + 1] = od * 2.0f;
    }
    __syncthreads();

    // stage 3: vertical upsample; each thread: 4 cols x 2 row-pairs; 8B stores
    int qx = tid & 15;
    int mg = tid >> 4;
    int gx0 = tx0 + 4 * qx;
    __fp16* upch = ups + (size_t)ch * CHELEMS;
#pragma unroll
    for (int pi = 0; pi < 2; ++pi) {
        int m = mg + pi * 16;
        int gy = ty0 + 2 * m;
        if (gy < HU) {
            if (gx0 + 3 < WU) {
                float4 r0 = *(const float4*)&s_mid[m + 0][4 * qx];
                float4 r1 = *(const float4*)&s_mid[m + 1][4 * qx];
                float4 r2 = *(const float4*)&s_mid[m + 2][4 * qx];
                float4 r3 = *(const float4*)&s_mid[m + 3][4 * qx];
                float4 r4 = *(const float4*)&s_mid[m + 4][4 * qx];
                float4 r5 = *(const float4*)&s_mid[m + 5][4 * qx];
                float4 r6 = *(const float4*)&s_mid[m + 6][4 * qx];
                float v0 = f[11]*r0.x + f[9]*r1.x + f[7]*r2.x + f[5]*r3.x + f[3]*r4.x + f[1]*r5.x;
                float v1 = f[11]*r0.y + f[9]*r1.y + f[7]*r2.y + f[5]*r3.y + f[3]*r4.y + f[1]*r5.y;
                float v2 = f[11]*r0.z + f[9]*r1.z + f[7]*r2.z + f[5]*r3.z + f[3]*r4.z + f[1]*r5.z;
                float v3 = f[11]*r0.w + f[9]*r1.w + f[7]*r2.w + f[5]*r3.w + f[3]*r4.w + f[1]*r5.w;
                float w0 = f[10]*r1.x + f[8]*r2.x + f[6]*r3.x + f[4]*r4.x + f[2]*r5.x + f[0]*r6.x;
                float w1 = f[10]*r1.y + f[8]*r2.y + f[6]*r3.y + f[4]*r4.y + f[2]*r5.y + f[0]*r6.y;
                float w2 = f[10]*r1.z + f[8]*r2.z + f[6]*r3.z + f[4]*r4.z + f[2]*r5.z + f[0]*r6.z;
                float w3 = f[10]*r1.w + f[8]*r2.w + f[6]*r3.w + f[4]*r4.w + f[2]*r5.w + f[0]*r6.w;
                uint2 qe, qo;
                qe.x = hbits(v0 * 2.0f, v1 * 2.0f); qe.y = hbits(v2 * 2.0f, v3 * 2.0f);
                qo.x = hbits(w0 * 2.0f, w1 * 2.0f); qo.y = hbits(w2 * 2.0f, w3 * 2.0f);
                *(uint2*)&upch[(size_t)gy * UPITCH + gx0]       = qe;
                *(uint2*)&upch[(size_t)(gy + 1) * UPITCH + gx0] = qo;
            } else if (gx0 >= WU && gx0 < UPITCH) {
                uint2 z; z.x = 0u; z.y = 0u;   // zero pad cols 664..671
                *(uint2*)&upch[(size_t)gy * UPITCH + gx0]       = z;
                *(uint2*)&upch[(size_t)(gy + 1) * UPITCH + gx0] = z;
            }
        }
    }
}

// ---------------- KB: LDS-staged bilinear warp + 2x downsample ----------------
// plain fp16 ups -> d_out [NIMG*CH, 256, 256]; 32x32 output tile; 74x74 warped grid.
// Source bbox staged into LDS coalesced (zeros baked for OOB); bilinear core uses
// ds_read2_b32 + v_alignbit packed pairs + fdot2.  Oversized bboxes (~2-3%) fall
// back to guarded global gather.
__global__ void __launch_bounds__(512) k_warpdn(const __fp16* __restrict__ ups,
                                                const float* __restrict__ coef,
                                                const float* __restrict__ hz,
                                                float* __restrict__ out,
                                                int n0, int ch0) {
    __shared__ __align__(16) unsigned char s_raw[PH * PWB];      // 40.1 KB
    __shared__ __fp16 s_wh[80 * 82];                             // 13.1 KB
    __fp16* s_src = (__fp16*)s_raw;
    h2*     s_m2  = (h2*)s_raw;      // aliases s_src (disjoint live ranges)

    int ch  = blockIdx.z;
    int ty0 = blockIdx.y * 32;
    int tx0 = blockIdx.x * 32;
    int tid = threadIdx.x;
    const float* cf = coef + (size_t)(n0 + ch / CH) * 6;
    float cxx = cf[0], cxy = cf[1], cx0 = cf[2];
    float cyx = cf[3], cyy = cf[4], cy0 = cf[5];
    const __fp16* upc = ups + (size_t)ch * CHELEMS;
    const unsigned short* us = (const unsigned short*)upc;
    int wy0 = 2 * ty0 + 1, wx0 = 2 * tx0 + 1;
    float wx0f = (float)wx0, wy0f = (float)wy0;

    // source bbox from tile corners (affine -> corners bound everything)
    float ix00 = cxx * wx0f + cxy * wy0f + cx0;
    float iy00 = cyx * wx0f + cyy * wy0f + cy0;
    float dxx = cxx * 73.0f, dxy = cxy * 73.0f;
    float dyx = cyx * 73.0f, dyy = cyy * 73.0f;
    float ixmin = ix00 + fminf(dxx, 0.0f) + fminf(dxy, 0.0f);
    float ixmax = ix00 + fmaxf(dxx, 0.0f) + fmaxf(dxy, 0.0f);
    float iymin = iy00 + fminf(dyx, 0.0f) + fminf(dyy, 0.0f);
    float iymax = iy00 + fmaxf(dyx, 0.0f) + fmaxf(dyy, 0.0f);
    int x_lo = (int)floorf(ixmin) - 1;
    int x_base = x_lo & ~7;
    int x_hi = (int)floorf(ixmax) + 2;
    int y_lo = (int)floorf(iymin) - 1;
    int y_hi = (int)floorf(iymax) + 2;
    int Rn = y_hi - y_lo + 1;
    int Wn = x_hi - x_base + 1;
    bool ldsok = (Rn <= PH) && (Wn <= PW);

    int wave = __builtin_amdgcn_readfirstlane(tid >> 6);   // 0..7
    int lane = tid & 63;
    int ply = lane >> 3, plx = lane & 7;
    float ix_l = cxx * (float)(wx0 + plx) + cxy * (float)(wy0 + ply) + cx0;
    float iy_l = cyx * (float)(wx0 + plx) + cyy * (float)(wy0 + ply) + cy0;
    float c8xx = 8.0f * cxx, c8xy = 8.0f * cxy;
    float c8yx = 8.0f * cyx, c8yy = 8.0f * cyy;

    if (ldsok) {
        // ---- stage bbox into LDS, coalesced 16B chunks, zero-fill OOB ----
        int slotsPerRow = (Wn + 7) >> 3;          // <= 19
        int items = Rn * (PW / 8);
        for (int i = tid; i < items; i += 512) {
            int row  = i / (PW / 8);
            int slot = i - row * (PW / 8);
            if (slot >= slotsPerRow) continue;    // unread slots stay garbage
            int gy = y_lo + row;
            int gx = x_base + slot * 8;
            uint4 val;
            if (gy >= 0 && gy < HU && gx >= 0 && gx <= UPITCH - 8) {
                val = *(const uint4*)&upc[(size_t)gy * UPITCH + gx];
            } else if (gy >= 0 && gy < HU) {
                unsigned part[4];
#pragma unroll
                for (int k = 0; k < 4; ++k) {
                    int ga = gx + 2 * k, gb = ga + 1;
                    unsigned lo = (ga >= 0 && ga < WU) ? (unsigned)us[(size_t)gy * UPITCH + ga] : 0u;
                    unsigned hi = (gb >= 0 && gb < WU) ? (unsigned)us[(size_t)gy * UPITCH + gb] : 0u;
                    part[k] = lo | (hi << 16);
                }
                val.x = part[0]; val.y = part[1]; val.z = part[2]; val.w = part[3];
            } else {
                val.x = 0u; val.y = 0u; val.z = 0u; val.w = 0u;
            }
            *(uint4*)&s_src[row * PW + slot * 8] = val;
        }
        __syncthreads();

        // ---- warp from LDS: ds_read2_b32 pairs + alignbit + fdot2 ----
        for (int pp = wave; pp < 100; pp += 8) {
            int py = (pp * 205) >> 11;     // pp/10, exact for 0..99
            int px = pp - py * 10;
            int lwy = py * 8 + ply;
            int lwx = px * 8 + plx;
            if (lwy < 74 && lwx < 74) {
                float ix = ix_l + (float)px * c8xx + (float)py * c8xy;
                float iy = iy_l + (float)px * c8yx + (float)py * c8yy;
                float fx = floorf(ix), fy = floorf(iy);
                float wx = ix - fx, wyf = iy - fy;
                int lx = (int)fx - x_base;
                int ly = (int)fy - y_lo;
                int e  = lx & ~1;
                unsigned sh = ((unsigned)lx & 1u) << 4;
                const unsigned* p0 = (const unsigned*)(s_raw + ly * PWB + 2 * e);
                unsigned w0 = p0[0], w1 = p0[1];
                const unsigned* p1 = (const unsigned*)((const unsigned char*)p0 + PWB);
                unsigned w2 = p1[0], w3 = p1[1];
                unsigned u0 = __builtin_amdgcn_alignbit(w1, w0, sh);
                unsigned u1 = __builtin_amdgcn_alignbit(w3, w2, sh);
                h2 h0; *(unsigned*)&h0 = u0;
                h2 h1; *(unsigned*)&h1 = u1;
                h2 wv = __builtin_amdgcn_cvt_pkrtz(1.0f - wx, wx);
                float r0 = __builtin_amdgcn_fdot2(h0, wv, 0.0f, false);
                float r1 = __builtin_amdgcn_fdot2(h1, wv, 0.0f, false);
                s_wh[lwy * 82 + lwx] = (__fp16)(r0 + wyf * (r1 - r0));
            }
        }
    } else {
        // ---- fallback: guarded global gather (rare: bbox too large) ----
        for (int pp = wave; pp < 100; pp += 8) {
            int py = (pp * 205) >> 11;
            int px = pp - py * 10;
            int lwy = py * 8 + ply;
            int lwx = px * 8 + plx;
            if (lwy < 74 && lwx < 74) {
                float ix = ix_l + (float)px * c8xx + (float)py * c8xy;
                float iy = iy_l + (float)px * c8yx + (float)py * c8yy;
                float fx = floorf(ix), fy = floorf(iy);
                float wx = ix - fx, wyf = iy - fy;
                int x0 = (int)fx, y0 = (int)fy;
                int xc0 = min(max(x0, 0), WU - 1);
                int xc1 = min(max(x0 + 1, 0), WU - 1);
                int yc0 = min(max(y0, 0), HU - 1);
                int yc1 = min(max(y0 + 1, 0), HU - 1);
                float mx0 = (x0 >= 0 && x0 < WU) ? 1.0f : 0.0f;
                float mx1 = (x0 >= -1 && x0 < WU - 1) ? 1.0f : 0.0f;
                float my0 = (y0 >= 0 && y0 < HU) ? 1.0f : 0.0f;
                float my1 = (y0 >= -1 && y0 < HU - 1) ? 1.0f : 0.0f;
                float t00 = (float)upc[(size_t)yc0 * UPITCH + xc0] * mx0;
                float t01 = (float)upc[(size_t)yc0 * UPITCH + xc1] * mx1;
                float t10 = (float)upc[(size_t)yc1 * UPITCH + xc0] * mx0;
                float t11 = (float)upc[(size_t)yc1 * UPITCH + xc1] * mx1;
                float r0 = t00 + wx * (t01 - t00);
                float r1 = t10 + wx * (t11 - t10);
                s_wh[lwy * 82 + lwx] = (__fp16)(r0 * (1.0f - wyf) * my0 + r1 * wyf * my1);
            }
        }
    }
    __syncthreads();

    // filter registers (loaded after gather phase)
    float f[12];
#pragma unroll
    for (int i = 0; i < 12; ++i) f[i] = hz[i];
    h2 Fe[6];
#pragma unroll
    for (int i = 0; i < 6; ++i) { Fe[i][0] = (__fp16)f[2 * i]; Fe[i][1] = (__fp16)f[2 * i + 1]; }

    // phase 2: horizontal downsample via fdot2 on fp16 pairs -> s_m2 (aliases s_src)
    for (int i = tid; i < 74 * 16; i += 512) {
        int j = i & 15, lwy = i >> 4;
        const __fp16* r = &s_wh[lwy * 82 + 4 * j];
        h2 P0 = *(const h2*)(r + 0);
        h2 P1 = *(const h2*)(r + 2);
        h2 P2 = *(const h2*)(r + 4);
        h2 P3 = *(const h2*)(r + 6);
        h2 P4 = *(const h2*)(r + 8);
        h2 P5 = *(const h2*)(r + 10);
        h2 P6 = *(const h2*)(r + 12);
        float ev = __builtin_amdgcn_fdot2(P0, Fe[0],
                   __builtin_amdgcn_fdot2(P1, Fe[1],
                   __builtin_amdgcn_fdot2(P2, Fe[2],
                   __builtin_amdgcn_fdot2(P3, Fe[3],
                   __builtin_amdgcn_fdot2(P4, Fe[4],
                   __builtin_amdgcn_fdot2(P5, Fe[5], 0.0f, false), false), false), false), false), false);
        float od = __builtin_amdgcn_fdot2(P1, Fe[0],
                   __builtin_amdgcn_fdot2(P2, Fe[1],
                   __builtin_amdgcn_fdot2(P3, Fe[2],
                   __builtin_amdgcn_fdot2(P4, Fe[3],
                   __builtin_amdgcn_fdot2(P5, Fe[4],
                   __builtin_amdgcn_fdot2(P6, Fe[5], 0.0f, false), false), false), false), false), false);
        h2 sm; sm[0] = (__fp16)ev; sm[1] = (__fp16)od;
        s_m2[lwy * 17 + j] = sm;
    }
    __syncthreads();

    // phase 3: vertical downsample, (even,odd) column pair per thread
    if (tid < 32 * 16) {
        int j = tid & 15, my = tid >> 4;
        float ev = 0.0f, od = 0.0f;
#pragma unroll
        for (int t = 0; t < 12; ++t) {
            h2 h = s_m2[(2 * my + t) * 17 + j];
            ev += f[t] * (float)h[0];
            od += f[t] * (float)h[1];
        }
        float2 o; o.x = ev; o.y = od;
        *(float2*)&out[(size_t)(ch0 + ch) * HO * WO + (size_t)(ty0 + my) * WO + (tx0 + 2 * j)] = o;
    }
}

// ---------------- launch ----------------
extern "C" void kernel_launch(void* const* d_in, const int* in_sizes, int n_in,
                              void* d_out, int out_size, void* d_ws, size_t ws_size,
                              hipStream_t stream) {
    const float* images = (const float*)d_in[0];
    const float* theta  = (const float*)d_in[1];
    const float* log_s  = (const float*)d_in[2];
    const float* tx     = (const float*)d_in[3];
    const float* ty     = (const float*)d_in[4];
    const float* hz     = (const float*)d_in[5];
    float* out = (float*)d_out;
    float* ws  = (float*)d_ws;

    // cn=32: single chunk (85.6 MB intermediate). vs cn=16: removes 2 dispatch
    // drain/launch gaps and makes warpdn 6144 blocks = 8 FULL residency rounds
    // (round-2 lesson: partial residency rounds are a 2x tail loss). L3-miss
    // downside is bounded: ~21 MB extra HBM refetch = ~3.4 us at 6.3 TB/s, and
    // round-2 counters showed ~30 MB FETCH per warpdn dispatch even at cn=16.
    int cn = 32;
    while (cn > 1) {
        size_t needed = 1024 + (size_t)cn * CH * CHELEMS * sizeof(__fp16);
        if (needed <= ws_size) break;
        cn >>= 1;
    }
    float* coef = ws;
    __fp16* upsb = (__fp16*)(ws + 256);

    hipLaunchKernelGGL(k_setup, dim3(1), dim3(32), 0, stream, theta, log_s, tx, ty, coef);

    const int TA = (HU + 63) / 64;    // 11
    for (int n0 = 0; n0 < NIMG; n0 += cn) {
        int nch = cn * CH;
        int ch0 = n0 * CH;
        hipLaunchKernelGGL(k_up2, dim3(TA, TA, nch), dim3(256), 0, stream,
                           images, hz, upsb, ch0);
        hipLaunchKernelGGL(k_warpdn, dim3(WO / 32, HO / 32, nch), dim3(512), 0, stream,
                           upsb, coef, hz, out, n0, ch0);
    }
}